// Round 8
// baseline (151.468 us; speedup 1.0000x reference)
//
#include <hip/hip_runtime.h>
#include <math.h>

#define DD 160
#define HH 160
#define WW 160
#define NB 2
#define SLICE (HH * WW)        // 25600
#define NV 51200               // NB*160*160 vectors per reduction type
#define NVTOT (4 * NV)         // gxH, gzH, gyD, gzD
#define NC 10                  // chunks per reduced axis
#define RPC 16                 // rows (slices) per chunk
#define NTHR 320               // 8 groups x 40 float4-lanes

static constexpr float EPS = 1e-12f;
static constexpr float SCALE = -1.0f / 960.0f;  // -(six cos sums)/(160*2*3)

#define ELEM(v, j) ((j) == 0 ? (v).x : ((j) == 1 ? (v).y : ((j) == 2 ? (v).z : (v).w)))

__global__ void zero_kernel(float* out) {
  if (threadIdx.x == 0) out[0] = 0.0f;
}

// ---------------------------------------------------------------------------
// Fused main pass (R7 skeleton). Key change vs R7: ALL of a row-pair's loads
// (10 f4 + 4 scalar for A, 8 f4 + 4 scalar for B) are hoisted and issued
// before any math — maximizing in-flight loads per wave (R7's VGPR=44 proved
// the compiler was serializing them). Row1's self reuses row0's h+1 load
// (register forward, no load dependence).
// ---------------------------------------------------------------------------
__global__ __launch_bounds__(NTHR) void mainAB(const float* __restrict__ f,
                                               const float* __restrict__ t,
                                               float* __restrict__ P,
                                               float* __restrict__ out) {
  __shared__ float sd[RPC * 40 * 7];    // 4480 f (17.9 KB); reused as dmp[4][40][25]
  __shared__ float red[RPC][6];
  __shared__ float cpad[RPC];
  const int tid = threadIdx.x;
  const int g = tid / 40;               // group 0..7
  const int l = tid % 40;               // float4-lane within row
  const int w = 4 * l;
  const int wn = (w + 4 < WW) ? (w + 4) : (WW - 1);  // clamp -> gz[3]=0 at w=159
  const int blk = blockIdx.x;
  const bool roleA = ((blk & 1) == 0);
  const int id = blk >> 1;

  float acc[24];                        // alongH (A) or alongD (B) partials
#pragma unroll
  for (int c = 0; c < 24; ++c) acc[c] = 0.0f;

  int vbase1, vbase2, ch;

  if (roleA) {
    // ---------------- role A (h-walk, pair of consecutive rows) ----------------
    const int hc = id % NC;
    const int bd = id / NC;
    const int d = bd % DD;
    const size_t base = (size_t)bd * SLICE;
    const float* fp = f + base;
    const float* tp = t + base;
    const int dstep = (d < DD - 1) ? SLICE : 0;     // clamp -> gx = 0
    vbase1 = bd * 160;                  // gx alongH
    vbase2 = NV + bd * 160;             // gz alongH
    ch = hc;
    const int h0 = hc * RPC + g * 2;    // h0 <= 158, so h0+1 always valid
    const float* rf0 = fp + h0 * WW;
    const float* rt0 = tp + h0 * WW;
    const float* rf1 = rf0 + WW;
    const float* rt1 = rt0 + WW;
    const int hstep1 = (h0 + 1 < HH - 1) ? WW : 0;  // clamp -> gy = 0 at h=159

    // ---- hoisted loads: 10 float4 + 4 scalar, all independent ----
    const float4 F0  = *(const float4*)(rf0 + w);
    const float4 T0  = *(const float4*)(rt0 + w);
    const float4 FD0 = *(const float4*)(rf0 + dstep + w);
    const float4 TD0 = *(const float4*)(rt0 + dstep + w);
    const float4 FH0 = *(const float4*)(rf1 + w);   // row h0+1 self == row0's h-neighbor
    const float4 TH0 = *(const float4*)(rt1 + w);
    const float4 FD1 = *(const float4*)(rf1 + dstep + w);
    const float4 TD1 = *(const float4*)(rt1 + dstep + w);
    const float4 FH1 = *(const float4*)(rf1 + hstep1 + w);
    const float4 TH1 = *(const float4*)(rt1 + hstep1 + w);
    const float fz0 = rf0[wn], tz0 = rt0[wn];
    const float fz1 = rf1[wn], tz1 = rt1[wn];

    // ---- math for both rows ----
    {
      float xd = 0, xf = 0, xt = 0, yd = 0, yf = 0, yt = 0;
#pragma unroll
      for (int j = 0; j < 4; ++j) {
        const float f0 = ELEM(F0, j), t0 = ELEM(T0, j);
        const float gxf = ELEM(FD0, j) - f0, gxt = ELEM(TD0, j) - t0;
        const float gyf = ELEM(FH0, j) - f0, gyt = ELEM(TH0, j) - t0;
        const float fnx = (j < 3) ? ELEM(F0, j + 1) : fz0;
        const float tnx = (j < 3) ? ELEM(T0, j + 1) : tz0;
        const float gzf = fnx - f0, gzt = tnx - t0;
        xd += gxf * gxt; xf += gxf * gxf; xt += gxt * gxt;
        yd += gyf * gyt; yf += gyf * gyf; yt += gyt * gyt;
        acc[j * 6 + 0] += gxf * gxt; acc[j * 6 + 1] += gxf * gxf; acc[j * 6 + 2] += gxt * gxt;
        acc[j * 6 + 3] += gzf * gzt; acc[j * 6 + 4] += gzf * gzf; acc[j * 6 + 5] += gzt * gzt;
      }
      float* s = &sd[((g * 2 + 0) * 40 + l) * 7];
      s[0] = xd; s[1] = xf; s[2] = xt; s[3] = yd; s[4] = yf; s[5] = yt;
    }
    {
      float xd = 0, xf = 0, xt = 0, yd = 0, yf = 0, yt = 0;
#pragma unroll
      for (int j = 0; j < 4; ++j) {
        const float f0 = ELEM(FH0, j), t0 = ELEM(TH0, j);
        const float gxf = ELEM(FD1, j) - f0, gxt = ELEM(TD1, j) - t0;
        const float gyf = ELEM(FH1, j) - f0, gyt = ELEM(TH1, j) - t0;
        const float fnx = (j < 3) ? ELEM(FH0, j + 1) : fz1;
        const float tnx = (j < 3) ? ELEM(TH0, j + 1) : tz1;
        const float gzf = fnx - f0, gzt = tnx - t0;
        xd += gxf * gxt; xf += gxf * gxf; xt += gxt * gxt;
        yd += gyf * gyt; yf += gyf * gyf; yt += gyt * gyt;
        acc[j * 6 + 0] += gxf * gxt; acc[j * 6 + 1] += gxf * gxf; acc[j * 6 + 2] += gxt * gxt;
        acc[j * 6 + 3] += gzf * gzt; acc[j * 6 + 4] += gzf * gzf; acc[j * 6 + 5] += gzt * gzt;
      }
      float* s = &sd[((g * 2 + 1) * 40 + l) * 7];
      s[0] = xd; s[1] = xf; s[2] = xt; s[3] = yd; s[4] = yf; s[5] = yt;
    }
    __syncthreads();
    // alongW reduce over 40 lanes: 96 tasks (16 rows x 6 sums)
    if (tid < RPC * 6) {
      const int row = tid / 6, c = tid % 6;
      float s = 0.0f;
#pragma unroll 8
      for (int ll = 0; ll < 40; ++ll) s += sd[(row * 40 + ll) * 7 + c];
      red[row][c] = s;
    }
    __syncthreads();                    // sd now free for reuse as dmp
    if (tid < RPC) {
      const float cx = red[tid][0] / (fmaxf(sqrtf(red[tid][1]), EPS) * fmaxf(sqrtf(red[tid][2]), EPS));
      const float cy = red[tid][3] / (fmaxf(sqrtf(red[tid][4]), EPS) * fmaxf(sqrtf(red[tid][5]), EPS));
      cpad[tid] = cx + cy;
    }
  } else {
    // ---------------- role B (d-walk, pair of consecutive slices) ----------------
    const int dc = id % NC;
    const int bh = id / NC;
    const int b = bh / HH;
    const int h = bh % HH;
    const float* fp = f + (size_t)b * DD * SLICE + (size_t)h * WW;
    const float* tp = t + (size_t)b * DD * SLICE + (size_t)h * WW;
    const int hstep = (h < HH - 1) ? WW : 0;        // clamp -> gy = 0
    vbase1 = 2 * NV + bh * 160;         // gy alongD
    vbase2 = 3 * NV + bh * 160;         // gz alongD
    ch = dc;
    const int d0 = dc * RPC + g * 2;
    const float* rf0 = fp + (size_t)d0 * SLICE;
    const float* rt0 = tp + (size_t)d0 * SLICE;
    const float* rf1 = rf0 + SLICE;
    const float* rt1 = rt0 + SLICE;

    // ---- hoisted loads: 8 float4 + 4 scalar, all independent ----
    const float4 F00 = *(const float4*)(rf0 + w);
    const float4 T00 = *(const float4*)(rt0 + w);
    const float4 FH0 = *(const float4*)(rf0 + hstep + w);
    const float4 TH0 = *(const float4*)(rt0 + hstep + w);
    const float4 F01 = *(const float4*)(rf1 + w);
    const float4 T01 = *(const float4*)(rt1 + w);
    const float4 FH1 = *(const float4*)(rf1 + hstep + w);
    const float4 TH1 = *(const float4*)(rt1 + hstep + w);
    const float fz0 = rf0[wn], tz0 = rt0[wn];
    const float fz1 = rf1[wn], tz1 = rt1[wn];

#pragma unroll
    for (int j = 0; j < 4; ++j) {
      const float f0 = ELEM(F00, j), t0 = ELEM(T00, j);
      const float gyf = ELEM(FH0, j) - f0, gyt = ELEM(TH0, j) - t0;
      const float fnx = (j < 3) ? ELEM(F00, j + 1) : fz0;
      const float tnx = (j < 3) ? ELEM(T00, j + 1) : tz0;
      const float gzf = fnx - f0, gzt = tnx - t0;
      acc[j * 6 + 0] += gyf * gyt; acc[j * 6 + 1] += gyf * gyf; acc[j * 6 + 2] += gyt * gyt;
      acc[j * 6 + 3] += gzf * gzt; acc[j * 6 + 4] += gzf * gzf; acc[j * 6 + 5] += gzt * gzt;
    }
#pragma unroll
    for (int j = 0; j < 4; ++j) {
      const float f0 = ELEM(F01, j), t0 = ELEM(T01, j);
      const float gyf = ELEM(FH1, j) - f0, gyt = ELEM(TH1, j) - t0;
      const float fnx = (j < 3) ? ELEM(F01, j + 1) : fz1;
      const float tnx = (j < 3) ? ELEM(T01, j + 1) : tz1;
      const float gzf = fnx - f0, gzt = tnx - t0;
      acc[j * 6 + 0] += gyf * gyt; acc[j * 6 + 1] += gyf * gyf; acc[j * 6 + 2] += gyt * gyt;
      acc[j * 6 + 3] += gzf * gzt; acc[j * 6 + 4] += gzf * gzf; acc[j * 6 + 5] += gzt * gzt;
    }
  }

  // ------- column combine: write-once hierarchical tree (no atomics) -------
  if (g >= 4) {
    float* s2 = &sd[(((g - 4) * 40 + l)) * 25];
#pragma unroll
    for (int c = 0; c < 24; ++c) s2[c] = acc[c];
  }
  __syncthreads();
  if (g < 4) {
    float* s2 = &sd[((g * 40 + l)) * 25];
#pragma unroll
    for (int c = 0; c < 24; ++c) s2[c] += acc[c];
  }
  __syncthreads();
  if (g < 2) {
    float* s2 = &sd[((g * 40 + l)) * 25];
    const float* s3 = &sd[(((g + 2) * 40 + l)) * 25];
#pragma unroll
    for (int c = 0; c < 24; ++c) s2[c] += s3[c];
  }
  __syncthreads();

  if (roleA && tid == 0) {
    float s = 0.0f;
#pragma unroll
    for (int i = 0; i < RPC; ++i) s += cpad[i];
    atomicAdd(out, s * SCALE);
  }
  if (tid < 160) {
    const int ll = tid >> 2, j = tid & 3;           // w-position wi = tid
    const size_t o1 = ((size_t)ch * NVTOT + (vbase1 + tid)) * 3;
    const size_t o2 = ((size_t)ch * NVTOT + (vbase2 + tid)) * 3;
    const float* a0 = &sd[(0 * 40 + ll) * 25 + j * 6];
    const float* a1 = &sd[(1 * 40 + ll) * 25 + j * 6];
    P[o1 + 0] = a0[0] + a1[0]; P[o1 + 1] = a0[1] + a1[1]; P[o1 + 2] = a0[2] + a1[2];
    P[o2 + 0] = a0[3] + a1[3]; P[o2 + 1] = a0[4] + a1[4]; P[o2 + 2] = a0[5] + a1[5];
  }
}

// ---------------------------------------------------------------------------
// Combine chunk partials -> cosines -> loss.
// ---------------------------------------------------------------------------
__global__ __launch_bounds__(256) void finalize_kernel(const float* __restrict__ P,
                                                       float* __restrict__ out) {
  const int v = blockIdx.x * 256 + threadIdx.x;
  float c = 0.0f;
  if (v < NVTOT) {
    float dot = 0.0f, ff = 0.0f, tt = 0.0f;
#pragma unroll
    for (int ch = 0; ch < NC; ++ch) {
      const size_t o = ((size_t)ch * NVTOT + v) * 3;
      dot += P[o]; ff += P[o + 1]; tt += P[o + 2];
    }
    c = dot / (fmaxf(sqrtf(ff), EPS) * fmaxf(sqrtf(tt), EPS));
  }
#pragma unroll
  for (int m = 32; m >= 1; m >>= 1) c += __shfl_xor(c, m);
  __shared__ float part[4];
  if ((threadIdx.x & 63) == 0) part[threadIdx.x >> 6] = c;
  __syncthreads();
  if (threadIdx.x == 0) atomicAdd(out, (part[0] + part[1] + part[2] + part[3]) * SCALE);
}

extern "C" void kernel_launch(void* const* d_in, const int* in_sizes, int n_in,
                              void* d_out, int out_size, void* d_ws, size_t ws_size,
                              hipStream_t stream) {
  const float* fk = (const float*)d_in[0];
  const float* tr = (const float*)d_in[1];
  float* out = (float*)d_out;
  float* P = (float*)d_ws;   // NC*NVTOT*3 floats = 24.6 MB

  hipLaunchKernelGGL(zero_kernel, dim3(1), dim3(64), 0, stream, out);
  hipLaunchKernelGGL(mainAB, dim3(2 * NB * DD * NC), dim3(NTHR), 0, stream, fk, tr, P, out);
  hipLaunchKernelGGL(finalize_kernel, dim3((NVTOT + 255) / 256), dim3(256), 0, stream, P, out);
}

// Round 9
// 145.457 us; speedup vs baseline: 1.0413x; 1.0413x over previous
//
#include <hip/hip_runtime.h>
#include <math.h>

#define DD 160
#define HH 160
#define WW 160
#define NB 2
#define SLICE (HH * WW)        // 25600
#define NV 51200               // NB*160*160 vectors per reduction type
#define Dt 4                   // d's per block
#define NDC 40                 // d-chunks (160/Dt)
#define NHC 10                 // h-chunks
#define HCS 16                 // rows per h-chunk
#define NTHR 320               // 8 groups x 40 float4-lanes

static constexpr float EPS = 1e-12f;
static constexpr float SCALE = -1.0f / 960.0f;  // -(six cos sums)/(160*2*3)

#define ELEM(v, j) ((j) == 0 ? (v).x : ((j) == 1 ? (v).y : ((j) == 2 ? (v).z : (v).w)))

__global__ void zero_kernel(float* out) {
  if (threadIdx.x == 0) out[0] = 0.0f;
}

// ---------------------------------------------------------------------------
// Single fused pass ("Design S"). Block = (b, d-chunk of 4, h-chunk of 16).
// Registers chain along D: the d-neighbor loads of phase p are the self values
// of phase p+1, so each element is loaded ~once (6 f4 + 4 scalar per thread
// per 2 rows per d). Per phase: alongW row cosines (gx,gy) + alongH partials
// (gx,gz) -> pH. alongD partials (gy,gz) accumulate in 48 persistent VGPRs
// across the 4 phases -> pD at block end. No atomics except the final scalar.
// ---------------------------------------------------------------------------
__global__ __launch_bounds__(NTHR, 2) void mainS(const float* __restrict__ f,
                                                 const float* __restrict__ t,
                                                 float* __restrict__ P,
                                                 float* __restrict__ out) {
  __shared__ float sw[HCS * 40 * 7];    // 4480 f: per-(row,lane) alongW partials
  __shared__ float sh[8 * 40 * 25];     // 8000 f: per-(group,lane) alongH partials
  __shared__ float red[HCS][6];
  __shared__ float cpad[HCS];
  const int tid = threadIdx.x;
  const int g = tid / 40;               // group 0..7
  const int l = tid % 40;               // float4-lane
  const int w = 4 * l;
  const int wn = (w + 4 < WW) ? (w + 4) : (WW - 1);  // clamp -> gz[3]=0 at w=159
  const int hc = blockIdx.x % NHC;
  const int t2 = blockIdx.x / NHC;
  const int dc = t2 % NDC;
  const int b  = t2 / NDC;
  const int d0 = dc * Dt;
  const int r0 = hc * HCS + g * 2;      // thread's two consecutive rows
  const int r1 = r0 + 1;
  const int r2 = (r1 + 1 < HH) ? (r1 + 1) : (HH - 1);  // clamp -> gy=0 at h=159
  const float* fb = f + (size_t)b * DD * SLICE;
  const float* tb = t + (size_t)b * DD * SLICE;
  float* pH = P;                                  // [NHC][6][NV], vec=(b,d,w)
  float* pD = P + (size_t)NHC * 6 * NV;           // [NDC][6][NV], vec=(b,h,w)

  // init chained self: slice d0, rows r0,r1 (+ wn scalars)
  float4 S0f = *(const float4*)(fb + (size_t)d0 * SLICE + r0 * WW + w);
  float4 S0t = *(const float4*)(tb + (size_t)d0 * SLICE + r0 * WW + w);
  float4 S1f = *(const float4*)(fb + (size_t)d0 * SLICE + r1 * WW + w);
  float4 S1t = *(const float4*)(tb + (size_t)d0 * SLICE + r1 * WW + w);
  float s0fz = (fb + (size_t)d0 * SLICE + r0 * WW)[wn];
  float s0tz = (tb + (size_t)d0 * SLICE + r0 * WW)[wn];
  float s1fz = (fb + (size_t)d0 * SLICE + r1 * WW)[wn];
  float s1tz = (tb + (size_t)d0 * SLICE + r1 * WW)[wn];

  float aD[48];                         // alongD (gy,gz) persistent accumulators
#pragma unroll
  for (int c = 0; c < 48; ++c) aD[c] = 0.0f;
  float accCos = 0.0f;

#pragma unroll
  for (int p = 0; p < Dt; ++p) {
    const int d = d0 + p;
    const int dn = (d + 1 < DD) ? (d + 1) : d;  // clamp -> gx = 0 at d=159
    const float* fS = fb + (size_t)d * SLICE;
    const float* tS = tb + (size_t)d * SLICE;
    const float* fN = fb + (size_t)dn * SLICE;
    const float* tN = tb + (size_t)dn * SLICE;
    // per-phase loads: 6 f4 + 4 scalars, all independent
    const float4 Hf  = *(const float4*)(fS + r2 * WW + w);   // row r2 self (gy for r1)
    const float4 Ht  = *(const float4*)(tS + r2 * WW + w);
    const float4 D0f = *(const float4*)(fN + r0 * WW + w);   // next-d self r0
    const float4 D0t = *(const float4*)(tN + r0 * WW + w);
    const float4 D1f = *(const float4*)(fN + r1 * WW + w);   // next-d self r1
    const float4 D1t = *(const float4*)(tN + r1 * WW + w);
    const float d0fz = (fN + r0 * WW)[wn], d0tz = (tN + r0 * WW)[wn];
    const float d1fz = (fN + r1 * WW)[wn], d1tz = (tN + r1 * WW)[wn];

    float aH[24];
#pragma unroll
    for (int c = 0; c < 24; ++c) aH[c] = 0.0f;

    // ---- row r0: gx = D0-S0, gy = S1-S0, gz = shift(S0) ----
    {
      float xd = 0, xf = 0, xt = 0, yd = 0, yf = 0, yt = 0;
#pragma unroll
      for (int j = 0; j < 4; ++j) {
        const float f0 = ELEM(S0f, j), t0 = ELEM(S0t, j);
        const float gxf = ELEM(D0f, j) - f0, gxt = ELEM(D0t, j) - t0;
        const float gyf = ELEM(S1f, j) - f0, gyt = ELEM(S1t, j) - t0;
        const float fnx = (j < 3) ? ELEM(S0f, j + 1) : s0fz;
        const float tnx = (j < 3) ? ELEM(S0t, j + 1) : s0tz;
        const float gzf = fnx - f0, gzt = tnx - t0;
        xd += gxf * gxt; xf += gxf * gxf; xt += gxt * gxt;
        yd += gyf * gyt; yf += gyf * gyf; yt += gyt * gyt;
        aH[j * 6 + 0] += gxf * gxt; aH[j * 6 + 1] += gxf * gxf; aH[j * 6 + 2] += gxt * gxt;
        aH[j * 6 + 3] += gzf * gzt; aH[j * 6 + 4] += gzf * gzf; aH[j * 6 + 5] += gzt * gzt;
        aD[j * 6 + 0] += gyf * gyt; aD[j * 6 + 1] += gyf * gyf; aD[j * 6 + 2] += gyt * gyt;
        aD[j * 6 + 3] += gzf * gzt; aD[j * 6 + 4] += gzf * gzf; aD[j * 6 + 5] += gzt * gzt;
      }
      float* s = &sw[((g * 2 + 0) * 40 + l) * 7];
      s[0] = xd; s[1] = xf; s[2] = xt; s[3] = yd; s[4] = yf; s[5] = yt;
    }
    // ---- row r1: gx = D1-S1, gy = H-S1, gz = shift(S1) ----
    {
      float xd = 0, xf = 0, xt = 0, yd = 0, yf = 0, yt = 0;
#pragma unroll
      for (int j = 0; j < 4; ++j) {
        const float f0 = ELEM(S1f, j), t0 = ELEM(S1t, j);
        const float gxf = ELEM(D1f, j) - f0, gxt = ELEM(D1t, j) - t0;
        const float gyf = ELEM(Hf, j) - f0, gyt = ELEM(Ht, j) - t0;
        const float fnx = (j < 3) ? ELEM(S1f, j + 1) : s1fz;
        const float tnx = (j < 3) ? ELEM(S1t, j + 1) : s1tz;
        const float gzf = fnx - f0, gzt = tnx - t0;
        xd += gxf * gxt; xf += gxf * gxf; xt += gxt * gxt;
        yd += gyf * gyt; yf += gyf * gyf; yt += gyt * gyt;
        aH[j * 6 + 0] += gxf * gxt; aH[j * 6 + 1] += gxf * gxf; aH[j * 6 + 2] += gxt * gxt;
        aH[j * 6 + 3] += gzf * gzt; aH[j * 6 + 4] += gzf * gzf; aH[j * 6 + 5] += gzt * gzt;
        aD[(4 + j) * 6 + 0] += gyf * gyt; aD[(4 + j) * 6 + 1] += gyf * gyf; aD[(4 + j) * 6 + 2] += gyt * gyt;
        aD[(4 + j) * 6 + 3] += gzf * gzt; aD[(4 + j) * 6 + 4] += gzf * gzf; aD[(4 + j) * 6 + 5] += gzt * gzt;
      }
      float* s = &sw[((g * 2 + 1) * 40 + l) * 7];
      s[0] = xd; s[1] = xf; s[2] = xt; s[3] = yd; s[4] = yf; s[5] = yt;
    }
    // dump alongH partials
    {
      float* s2 = &sh[(g * 40 + l) * 25];
#pragma unroll
      for (int c = 0; c < 24; ++c) s2[c] = aH[c];
    }
    // register chain: next phase's selves are this phase's d-neighbors
    S0f = D0f; S0t = D0t; S1f = D1f; S1t = D1t;
    s0fz = d0fz; s0tz = d0tz; s1fz = d1fz; s1tz = d1tz;
    __syncthreads();

    if (tid < 240) {
      // alongH reduce over 8 groups + coalesced f4 write to pH
      const int cc = tid / 40, ll = tid % 40;
      float v0 = 0, v1 = 0, v2 = 0, v3 = 0;
#pragma unroll
      for (int gg = 0; gg < 8; ++gg) {
        const float* q = &sh[(gg * 40 + ll) * 25];
        v0 += q[0 * 6 + cc]; v1 += q[1 * 6 + cc]; v2 += q[2 * 6 + cc]; v3 += q[3 * 6 + cc];
      }
      const int bd = b * DD + d;
      float4 o; o.x = v0; o.y = v1; o.z = v2; o.w = v3;
      *(float4*)(pH + ((size_t)(hc * 6 + cc)) * NV + bd * 160 + 4 * ll) = o;
    } else {
      // alongW reduce over 40 lanes: 96 tasks on 80 threads
      for (int k = tid - 240; k < HCS * 6; k += 80) {
        const int row = k / 6, c = k % 6;
        float s = 0.0f;
#pragma unroll 8
        for (int ll = 0; ll < 40; ++ll) s += sw[(row * 40 + ll) * 7 + c];
        red[row][c] = s;
      }
    }
    __syncthreads();
    if (tid < HCS) {
      const float cx = red[tid][0] / (fmaxf(sqrtf(red[tid][1]), EPS) * fmaxf(sqrtf(red[tid][2]), EPS));
      const float cy = red[tid][3] / (fmaxf(sqrtf(red[tid][4]), EPS) * fmaxf(sqrtf(red[tid][5]), EPS));
      accCos += cx + cy;
    }
  }

  // ---- alongD partials: 12 coalesced f4 writes per thread ----
#pragma unroll
  for (int r = 0; r < 2; ++r) {
    const int h = r0 + r;
#pragma unroll
    for (int cc = 0; cc < 6; ++cc) {
      float4 o;
      o.x = aD[(r * 4 + 0) * 6 + cc];
      o.y = aD[(r * 4 + 1) * 6 + cc];
      o.z = aD[(r * 4 + 2) * 6 + cc];
      o.w = aD[(r * 4 + 3) * 6 + cc];
      *(float4*)(pD + ((size_t)(dc * 6 + cc)) * NV + b * SLICE + h * 160 + 4 * l) = o;
    }
  }

  if (tid < HCS) cpad[tid] = accCos;
  __syncthreads();
  if (tid == 0) {
    float s = 0.0f;
#pragma unroll
    for (int i = 0; i < HCS; ++i) s += cpad[i];
    atomicAdd(out, s * SCALE);
  }
}

// ---------------------------------------------------------------------------
// Combine chunk partials -> cosines -> loss.
// types: 0 gx-alongH, 1 gz-alongH (sum 10 hc); 2 gy-alongD, 3 gz-alongD (sum 40 dc).
// ---------------------------------------------------------------------------
__global__ __launch_bounds__(256) void finalize_kernel(const float* __restrict__ P,
                                                       float* __restrict__ out) {
  const int v = blockIdx.x * 256 + threadIdx.x;
  float c = 0.0f;
  if (v < 4 * NV) {
    const int type = v / NV;
    const int vec = v % NV;
    float dot = 0.0f, ff = 0.0f, tt = 0.0f;
    if (type < 2) {
#pragma unroll
      for (int ch = 0; ch < NHC; ++ch) {
        const float* q = P + ((size_t)(ch * 6 + type * 3)) * NV + vec;
        dot += q[0]; ff += q[(size_t)NV]; tt += q[2 * (size_t)NV];
      }
    } else {
      const float* pD = P + (size_t)NHC * 6 * NV;
#pragma unroll 8
      for (int ch = 0; ch < NDC; ++ch) {
        const float* q = pD + ((size_t)(ch * 6 + (type - 2) * 3)) * NV + vec;
        dot += q[0]; ff += q[(size_t)NV]; tt += q[2 * (size_t)NV];
      }
    }
    c = dot / (fmaxf(sqrtf(ff), EPS) * fmaxf(sqrtf(tt), EPS));
  }
#pragma unroll
  for (int m = 32; m >= 1; m >>= 1) c += __shfl_xor(c, m);
  __shared__ float part[4];
  if ((threadIdx.x & 63) == 0) part[threadIdx.x >> 6] = c;
  __syncthreads();
  if (threadIdx.x == 0) atomicAdd(out, (part[0] + part[1] + part[2] + part[3]) * SCALE);
}

extern "C" void kernel_launch(void* const* d_in, const int* in_sizes, int n_in,
                              void* d_out, int out_size, void* d_ws, size_t ws_size,
                              hipStream_t stream) {
  const float* fk = (const float*)d_in[0];
  const float* tr = (const float*)d_in[1];
  float* out = (float*)d_out;
  float* P = (float*)d_ws;   // (NHC+NDC)*6*NV floats = 61.4 MB

  hipLaunchKernelGGL(zero_kernel, dim3(1), dim3(64), 0, stream, out);
  hipLaunchKernelGGL(mainS, dim3(NB * NDC * NHC), dim3(NTHR), 0, stream, fk, tr, P, out);
  hipLaunchKernelGGL(finalize_kernel, dim3((4 * NV + 255) / 256), dim3(256), 0, stream, P, out);
}